// Round 3
// baseline (1817.772 us; speedup 1.0000x reference)
//
#include <hip/hip_runtime.h>
#include <math.h>

typedef _Float16 f16;
typedef f16 f16x8 __attribute__((ext_vector_type(8)));
typedef float f32x4 __attribute__((ext_vector_type(4)));

#define MFMA16(a, b, c) __builtin_amdgcn_mfma_f32_16x16x32_f16((a), (b), (c), 0, 0, 0)

// ---------------------------------------------------------------------------
// ws layout (bytes):
//  Wg_t  fp16 [512][448]  @ 0        (gates t: cols 0:300 Wih, 320:448 Whh, rows interleaved n=4u+g)
//  Wg_a  fp16 [256][160]  @ 458752   (cols 0:81 Wih, 96:160 Whh)
//  Wg_v  fp16 [256][448]  @ 540672   (cols 0:371 Wih, 384:448 Whh)
//  W_a1  fp16 [128][512]  @ 770048   attn1_W1
//  W_a2  fp16 [512][128]  @ 901120   attn1_W2
//  W_b1  fp16 [128][512]  @ 1032192  attn2_W1
//  W_b2  fp16 [256][128]  @ 1163264  attn2_W2
//  W_g1  fp16 [256][768]  @ 1228800  rows 0:128 g1_W1, 128:256 g2_W1
//  W_g2  fp16 [512][128]  @ 1622016  rows 0:256 g1_W2, 256:512 g2_W2
//  W_o1  fp16 [128][512]  @ 1753088  out_W1
//  bg    f32  [1024]      @ 1884160  gate bias, interleaved layout
// ---------------------------------------------------------------------------

struct PackArgs {
  const float *t_Wih, *t_Whh, *t_b, *a_Wih, *a_Whh, *a_b, *v_Wih, *v_Whh, *v_b;
  const float *aW1, *aW2, *bW1, *bW2, *g1W1, *g2W1, *g1W2, *g2W2, *oW1;
  f16 *Wg_t, *Wg_a, *Wg_v, *W_a1, *W_a2, *W_b1, *W_b2, *W_g1, *W_g2, *W_o1;
  float *bg;
};

__global__ __launch_bounds__(256) void pack_w(PackArgs p) {
  int idx = blockIdx.x * 256 + threadIdx.x;
  if (idx < 229376) {  // Wg_t [512][448]
    int n = idx / 448, k = idx % 448;
    int srow = (n & 3) * 128 + (n >> 2);
    float v = (k < 300) ? p.t_Wih[srow * 300 + k]
                        : ((k >= 320) ? p.t_Whh[srow * 128 + k - 320] : 0.f);
    p.Wg_t[idx] = (f16)v; return;
  }
  idx -= 229376;
  if (idx < 40960) {  // Wg_a [256][160]
    int n = idx / 160, k = idx % 160;
    int srow = (n & 3) * 64 + (n >> 2);
    float v = (k < 81) ? p.a_Wih[srow * 81 + k]
                       : ((k >= 96) ? p.a_Whh[srow * 64 + k - 96] : 0.f);
    p.Wg_a[idx] = (f16)v; return;
  }
  idx -= 40960;
  if (idx < 114688) {  // Wg_v [256][448]
    int n = idx / 448, k = idx % 448;
    int srow = (n & 3) * 64 + (n >> 2);
    float v = (k < 371) ? p.v_Wih[srow * 371 + k]
                        : ((k >= 384) ? p.v_Whh[srow * 64 + k - 384] : 0.f);
    p.Wg_v[idx] = (f16)v; return;
  }
  idx -= 114688;
  if (idx < 65536) { p.W_a1[idx] = (f16)p.aW1[idx]; return; }
  idx -= 65536;
  if (idx < 65536) { p.W_a2[idx] = (f16)p.aW2[idx]; return; }
  idx -= 65536;
  if (idx < 65536) { p.W_b1[idx] = (f16)p.bW1[idx]; return; }
  idx -= 65536;
  if (idx < 32768) { p.W_b2[idx] = (f16)p.bW2[idx]; return; }
  idx -= 32768;
  if (idx < 196608) {  // W_g1 [256][768]
    int n = idx / 768;
    p.W_g1[idx] = (f16)((n < 128) ? p.g1W1[idx] : p.g2W1[idx - 98304]);
    return;
  }
  idx -= 196608;
  if (idx < 65536) {  // W_g2 [512][128]
    int n = idx / 128;
    p.W_g2[idx] = (f16)((n < 256) ? p.g1W2[idx] : p.g2W2[idx - 32768]);
    return;
  }
  idx -= 65536;
  if (idx < 65536) { p.W_o1[idx] = (f16)p.oW1[idx]; return; }
  idx -= 65536;
  if (idx < 1024) {  // bg
    int n = idx;
    float v;
    if (n < 512)      v = p.t_b[(n & 3) * 128 + (n >> 2)];
    else if (n < 768) { int m = n - 512; v = p.a_b[(m & 3) * 64 + (m >> 2)]; }
    else              { int m = n - 768; v = p.v_b[(m & 3) * 64 + (m >> 2)]; }
    p.bg[n] = v;
  }
}

struct MainArgs {
  const float *x_p, *c_t, *c_a, *c_v, *mem0;
  const f16 *Wg_t, *Wg_a, *Wg_v, *W_a1, *W_a2, *W_b1, *W_b2, *W_g1, *W_g2, *W_o1;
  const float *bg, *a1b1, *a1b2, *a2b1, *a2b2, *g1b1, *g1b2, *g2b1, *g2b2, *ob1, *oW2, *ob2;
  float *out;
};

__device__ __forceinline__ float sigm(float x) {
  return __builtin_amdgcn_rcpf(1.f + __expf(-x));
}
__device__ __forceinline__ float ftanh(float x) {
  float t = __expf(-2.f * fabsf(x));
  float r = (1.f - t) * __builtin_amdgcn_rcpf(1.f + t);
  return copysignf(r, x);
}

// ---- gate stage: load x/h fragments (static shapes per role) ---------------
template <int KSX, int KSH, int KXR>
__device__ __forceinline__ void gate_load(const float* xrow, int hb,
                                          f16x8* ax, f16x8* ah,
                                          const f16 (*h16)[264], int l15, int lg) {
#pragma unroll
  for (int ks = 0; ks < KSX; ++ks) {
    int kk = 32 * ks + 8 * lg;
    float t0[8];
    if (kk + 8 <= KXR) {
      float4 p0 = *(const float4*)(xrow + kk);
      float4 p1 = *(const float4*)(xrow + kk + 4);
      t0[0] = p0.x; t0[1] = p0.y; t0[2] = p0.z; t0[3] = p0.w;
      t0[4] = p1.x; t0[5] = p1.y; t0[6] = p1.z; t0[7] = p1.w;
    } else {
#pragma unroll
      for (int j = 0; j < 8; ++j) t0[j] = (kk + j < KXR) ? xrow[kk + j] : 0.f;
    }
    f16x8 vv;
#pragma unroll
    for (int j = 0; j < 8; ++j) vv[j] = (f16)t0[j];
    ax[ks] = vv;
  }
#pragma unroll
  for (int ks = 0; ks < KSH; ++ks)
    ah[ks] = *(const f16x8*)(&h16[l15][hb + 8 * lg + 32 * ks]);
}

// ---- gate stage: MFMA over 8 n-tiles, 2-deep weight prefetch, LSTM epilogue
template <int KSX, int KSH, int KP>
__device__ __forceinline__ void gate_mm(const f16* Wc, const float* bg,
                                        int nc0, int n0, int cub,
                                        const f16x8* ax, const f16x8* ah,
                                        int l15, int lg, int lane,
                                        f16 (*h16)[264], float (*cS)[260],
                                        f16 (*bufA)[808]) {
  constexpr int NF = KSX + KSH;
  const f16* wbase = Wc + (size_t)(nc0 + l15) * KP + 8 * lg;
  f16x8 wc[NF], wn[NF];
#pragma unroll
  for (int k = 0; k < NF; ++k) wc[k] = *(const f16x8*)(wbase + 32 * k);
#pragma unroll
  for (int i = 0; i < 8; ++i) {
    if (i < 7) {
      const f16* wb = wbase + (size_t)(i + 1) * 16 * KP;
#pragma unroll
      for (int k = 0; k < NF; ++k) wn[k] = *(const f16x8*)(wb + 32 * k);
    }
    f32x4 acc = {0.f, 0.f, 0.f, 0.f};
#pragma unroll
    for (int k = 0; k < KSX; ++k) acc = MFMA16(ax[k], wc[k], acc);
#pragma unroll
    for (int k = 0; k < KSH; ++k) acc = MFMA16(ah[k], wc[KSX + k], acc);
    float bias = bg[n0 + 16 * i + l15];
#pragma unroll
    for (int q = 0; q < 4; ++q) {
      float z = acc[q] + bias;
      float v = ((lane & 3) == 2) ? ftanh(z) : sigm(z);
      float vf = __shfl_xor(v, 1);
      float vg = __shfl_xor(v, 2);
      float vo = __shfl_xor(v, 3);
      if ((lane & 3) == 0) {  // v=sig(i), vf=sig(f), vg=tanh(g), vo=sig(o)
        int cu = cub + ((nc0 + 16 * i + l15) >> 2);
        int row = lg * 4 + q;
        float cold = cS[row][cu];
        float cnew = vf * cold + v * vg;
        cS[row][cu] = cnew;
        h16[row][cu] = (f16)(vo * ftanh(cnew));
        bufA[row][cu] = (f16)cold;
        bufA[row][256 + cu] = (f16)cnew;
      }
    }
#pragma unroll
    for (int k = 0; k < NF; ++k) wc[k] = wn[k];
  }
}

// ---- one 16-col output tile, K = KS*32, A from LDS ------------------------
template <int KS, int LDA>
__device__ __forceinline__ f32x4 fc_tile(const f16 (*Asrc)[LDA], int acol,
                                         const f16* Wrow, int l15, int lg) {
  f16x8 w[KS], a[KS];
#pragma unroll
  for (int k = 0; k < KS; ++k) w[k] = *(const f16x8*)(Wrow + 32 * k);
#pragma unroll
  for (int k = 0; k < KS; ++k)
    a[k] = *(const f16x8*)(&Asrc[l15][acol + 8 * lg + 32 * k]);
  f32x4 acc = {0.f, 0.f, 0.f, 0.f};
#pragma unroll
  for (int k = 0; k < KS; ++k) acc = MFMA16(a[k], w[k], acc);
  return acc;
}

// ---- g-hidden: K=768 from bufA, TILES 16-col tiles starting at tile st ----
template <int TILES>
__device__ __forceinline__ void ghidden_fn(const f16 (*bufA)[808], f16 (*ghid)[264],
                                           const f16* Wg1, const float* g1b1,
                                           const float* g2b1, int st, int l15, int lg) {
  f16x8 a[24];
#pragma unroll
  for (int k = 0; k < 24; ++k) a[k] = *(const f16x8*)(&bufA[l15][8 * lg + 32 * k]);
#pragma unroll
  for (int i = 0; i < TILES; ++i) {
    int nn = 16 * (st + i) + l15;
    const f16* wr = Wg1 + (size_t)nn * 768 + 8 * lg;
    f16x8 w[24];
#pragma unroll
    for (int k = 0; k < 24; ++k) w[k] = *(const f16x8*)(wr + 32 * k);
    f32x4 acc = {0.f, 0.f, 0.f, 0.f};
#pragma unroll
    for (int k = 0; k < 24; ++k) acc = MFMA16(a[k], w[k], acc);
    float b = (nn < 128) ? g1b1[nn] : g2b1[nn - 128];
#pragma unroll
    for (int q = 0; q < 4; ++q) ghid[lg * 4 + q][nn] = (f16)fmaxf(acc[q] + b, 0.f);
  }
}

__global__ __launch_bounds__(512, 2) void fused_seq(MainArgs A) {
  __shared__ f16  h16[16][264];     // current h (fp16)
  __shared__ float cS[16][260];     // cell state f32
  __shared__ float mS[16][260];     // memory f32
  __shared__ f16  bufA[16][808];    // cstar/attended (0:512) | m fp16 (512:768)
  __shared__ f16  hid16[16][264];   // attn MLP hidden
  __shared__ f16  ghid16[16][264];  // g1|g2 hidden
  __shared__ float zf[16][516];     // attn1 logits
  __shared__ float chat[16][260];   // c_hat f32

  const int tid = threadIdx.x;
  const int wid = tid >> 6, lane = tid & 63, l15 = lane & 15, lg = lane >> 4;
  const int r0 = blockIdx.x * 16;

  // ---- init state ----
  for (int idx = tid; idx < 4096; idx += 512) {
    int r = idx >> 8, c = idx & 255, R = r0 + r;
    h16[r][c] = (f16)0.f;
    float cv = (c < 128) ? A.c_t[R * 128 + c]
                         : (c < 192 ? A.c_a[R * 64 + c - 128] : A.c_v[R * 64 + c - 192]);
    cS[r][c] = cv;
    mS[r][c] = A.mem0[R * 256 + c];
  }
  __syncthreads();

#pragma unroll 1
  for (int t = 0; t < 20; ++t) {
    // ================= STAGE G: LSTM gates =================================
    const float* xrow = A.x_p + ((size_t)t * 4096 + r0 + l15) * 752;
    f16x8 ax[12], ah[4];
    if (wid < 4)      gate_load<10, 4, 300>(xrow,       0,   ax, ah, h16, l15, lg);
    else if (wid < 6) gate_load<3, 2, 81>(xrow + 300, 128, ax, ah, h16, l15, lg);
    else              gate_load<12, 2, 371>(xrow + 381, 192, ax, ah, h16, l15, lg);
    __syncthreads();  // frags in regs before h16/bufA/cS writes
    if (wid < 4)
      gate_mm<10, 4, 448>(A.Wg_t, A.bg, 128 * wid, 128 * wid, 0, ax, ah, l15, lg, lane, h16, cS, bufA);
    else if (wid < 6)
      gate_mm<3, 2, 160>(A.Wg_a, A.bg, 128 * (wid - 4), 512 + 128 * (wid - 4), 128, ax, ah, l15, lg, lane, h16, cS, bufA);
    else
      gate_mm<12, 2, 448>(A.Wg_v, A.bg, 128 * (wid - 6), 768 + 128 * (wid - 6), 192, ax, ah, l15, lg, lane, h16, cS, bufA);
    __syncthreads();

    // ================= attn1 L1: hid = relu(cstar @ W^T + b) ===============
    {
      int n = 16 * wid;
      f32x4 acc = fc_tile<16, 808>(bufA, 0, A.W_a1 + (size_t)(n + l15) * 512 + 8 * lg, l15, lg);
      float b = A.a1b1[n + l15];
#pragma unroll
      for (int q = 0; q < 4; ++q) hid16[lg * 4 + q][n + l15] = (f16)fmaxf(acc[q] + b, 0.f);
    }
    __syncthreads();

    // ================= attn1 L2: logits (4 tiles/wave, batched loads) ======
    {
      f16x8 a[4];
#pragma unroll
      for (int k = 0; k < 4; ++k) a[k] = *(const f16x8*)(&hid16[l15][8 * lg + 32 * k]);
      f16x8 w[4][4];
#pragma unroll
      for (int i = 0; i < 4; ++i) {
        const f16* wr = A.W_a2 + (size_t)(64 * wid + 16 * i + l15) * 128 + 8 * lg;
#pragma unroll
        for (int k = 0; k < 4; ++k) w[i][k] = *(const f16x8*)(wr + 32 * k);
      }
      f32x4 acc[4] = {{0.f,0.f,0.f,0.f},{0.f,0.f,0.f,0.f},{0.f,0.f,0.f,0.f},{0.f,0.f,0.f,0.f}};
#pragma unroll
      for (int k = 0; k < 4; ++k)
#pragma unroll
        for (int i = 0; i < 4; ++i) acc[i] = MFMA16(a[k], w[i][k], acc[i]);
#pragma unroll
      for (int i = 0; i < 4; ++i) {
        int n = 64 * wid + 16 * i + l15;
        float b = A.a1b2[n];
#pragma unroll
        for (int q = 0; q < 4; ++q) zf[lg * 4 + q][n] = acc[i][q] + b;
      }
    }
    __syncthreads();

    // ================= softmax * cstar (in place), m -> bufA[512:768] ======
    {
      int row = tid >> 5, c0 = tid & 31;
      float v[16]; float mx = -1e30f;
#pragma unroll
      for (int j = 0; j < 16; ++j) { v[j] = zf[row][c0 + 32 * j]; mx = fmaxf(mx, v[j]); }
#pragma unroll
      for (int m = 1; m < 32; m <<= 1) mx = fmaxf(mx, __shfl_xor(mx, m));
      float s = 0.f;
#pragma unroll
      for (int j = 0; j < 16; ++j) { v[j] = __expf(v[j] - mx); s += v[j]; }
#pragma unroll
      for (int m = 1; m < 32; m <<= 1) s += __shfl_xor(s, m);
      float inv = __builtin_amdgcn_rcpf(s);
#pragma unroll
      for (int j = 0; j < 16; ++j) {
        int c = c0 + 32 * j;
        bufA[row][c] = (f16)(v[j] * inv * (float)bufA[row][c]);
      }
      for (int idx = tid; idx < 4096; idx += 512) {
        int r = idx >> 8, c = idx & 255;
        bufA[r][512 + c] = (f16)mS[r][c];
      }
    }
    __syncthreads();

    // ================= attn2 L1: hid = relu(attended @ W^T + b) ============
    {
      int n = 16 * wid;
      f32x4 acc = fc_tile<16, 808>(bufA, 0, A.W_b1 + (size_t)(n + l15) * 512 + 8 * lg, l15, lg);
      float b = A.a2b1[n + l15];
#pragma unroll
      for (int q = 0; q < 4; ++q) hid16[lg * 4 + q][n + l15] = (f16)fmaxf(acc[q] + b, 0.f);
    }
    __syncthreads();

    // ====== attn2 L2 (waves 6,7) || g-hidden (waves 0-5, K=768) ============
    if (wid >= 6) {
      f16x8 a[4];
#pragma unroll
      for (int k = 0; k < 4; ++k) a[k] = *(const f16x8*)(&hid16[l15][8 * lg + 32 * k]);
      const f16* wr0 = A.W_b2 + (size_t)(128 * (wid - 6) + l15) * 128 + 8 * lg;
      f16x8 wc[4], wn[4];
#pragma unroll
      for (int k = 0; k < 4; ++k) wc[k] = *(const f16x8*)(wr0 + 32 * k);
#pragma unroll
      for (int i = 0; i < 8; ++i) {
        if (i < 7) {
          const f16* wr = wr0 + (size_t)(i + 1) * 16 * 128;
#pragma unroll
          for (int k = 0; k < 4; ++k) wn[k] = *(const f16x8*)(wr + 32 * k);
        }
        f32x4 acc = {0.f, 0.f, 0.f, 0.f};
#pragma unroll
        for (int k = 0; k < 4; ++k) acc = MFMA16(a[k], wc[k], acc);
        int n = 128 * (wid - 6) + 16 * i + l15;
        float b = A.a2b2[n];
#pragma unroll
        for (int q = 0; q < 4; ++q) chat[lg * 4 + q][n] = ftanh(acc[q] + b);
#pragma unroll
        for (int k = 0; k < 4; ++k) wc[k] = wn[k];
      }
    } else if (wid < 4) {
      ghidden_fn<3>(bufA, ghid16, A.W_g1, A.g1b1, A.g2b1, 3 * wid, l15, lg);
    } else {
      ghidden_fn<2>(bufA, ghid16, A.W_g1, A.g1b1, A.g2b1, 12 + 2 * (wid - 4), l15, lg);
    }
    __syncthreads();

    // ========== fused g second layers + memory update (per-wave cols) ======
    {
      f16x8 a1[4], a2[4];
#pragma unroll
      for (int k = 0; k < 4; ++k) {
        a1[k] = *(const f16x8*)(&ghid16[l15][8 * lg + 32 * k]);
        a2[k] = *(const f16x8*)(&ghid16[l15][128 + 8 * lg + 32 * k]);
      }
      f16x8 w1[2][4], w2[2][4];
#pragma unroll
      for (int i = 0; i < 2; ++i) {
        const f16* r1 = A.W_g2 + (size_t)(32 * wid + 16 * i + l15) * 128 + 8 * lg;
        const f16* r2 = A.W_g2 + (size_t)(256 + 32 * wid + 16 * i + l15) * 128 + 8 * lg;
#pragma unroll
        for (int k = 0; k < 4; ++k) {
          w1[i][k] = *(const f16x8*)(r1 + 32 * k);
          w2[i][k] = *(const f16x8*)(r2 + 32 * k);
        }
      }
      f32x4 ac1[2] = {{0.f,0.f,0.f,0.f},{0.f,0.f,0.f,0.f}};
      f32x4 ac2[2] = {{0.f,0.f,0.f,0.f},{0.f,0.f,0.f,0.f}};
#pragma unroll
      for (int k = 0; k < 4; ++k)
#pragma unroll
        for (int i = 0; i < 2; ++i) {
          ac1[i] = MFMA16(a1[k], w1[i][k], ac1[i]);
          ac2[i] = MFMA16(a2[k], w2[i][k], ac2[i]);
        }
#pragma unroll
      for (int i = 0; i < 2; ++i) {
        int col = 32 * wid + 16 * i + l15;
        float b1 = A.g1b2[col], b2 = A.g2b2[col];
#pragma unroll
        for (int q = 0; q < 4; ++q) {
          float g1 = sigm(ac1[i][q] + b1);
          float g2 = sigm(ac2[i][q] + b2);
          int row = lg * 4 + q;
          mS[row][col] = g1 * mS[row][col] + g2 * chat[row][col];
        }
      }
    }
    __syncthreads();
  }

  // ================= output head ==========================================
  for (int idx = tid; idx < 4096; idx += 512) {
    int r = idx >> 8, c = idx & 255;
    bufA[r][c] = h16[r][c];
    bufA[r][256 + c] = (f16)mS[r][c];
  }
  __syncthreads();
  {
    int n = 16 * wid;
    f32x4 acc = fc_tile<16, 808>(bufA, 0, A.W_o1 + (size_t)(n + l15) * 512 + 8 * lg, l15, lg);
    float b = A.ob1[n + l15];
#pragma unroll
    for (int q = 0; q < 4; ++q) hid16[lg * 4 + q][n + l15] = (f16)fmaxf(acc[q] + b, 0.f);
  }
  __syncthreads();
  {
    int row = tid >> 5, c0 = tid & 31;
    float s = 0.f;
#pragma unroll
    for (int j = 0; j < 4; ++j) { int k = c0 + 32 * j; s += (float)hid16[row][k] * A.oW2[k]; }
#pragma unroll
    for (int m = 1; m < 32; m <<= 1) s += __shfl_xor(s, m);
    if (c0 == 0) A.out[r0 + row] = s + A.ob2[0];
  }
}

extern "C" void kernel_launch(void* const* d_in, const int* in_sizes, int n_in,
                              void* d_out, int out_size, void* d_ws, size_t ws_size,
                              hipStream_t stream) {
  (void)in_sizes; (void)n_in; (void)out_size; (void)ws_size;
  char* w = (char*)d_ws;
  f16* Wg_t = (f16*)(w + 0);
  f16* Wg_a = (f16*)(w + 458752);
  f16* Wg_v = (f16*)(w + 540672);
  f16* W_a1 = (f16*)(w + 770048);
  f16* W_a2 = (f16*)(w + 901120);
  f16* W_b1 = (f16*)(w + 1032192);
  f16* W_b2 = (f16*)(w + 1163264);
  f16* W_g1 = (f16*)(w + 1228800);
  f16* W_g2 = (f16*)(w + 1622016);
  f16* W_o1 = (f16*)(w + 1753088);
  float* bg = (float*)(w + 1884160);

  PackArgs pa;
  pa.t_Wih = (const float*)d_in[5];  pa.t_Whh = (const float*)d_in[6];  pa.t_b = (const float*)d_in[7];
  pa.a_Wih = (const float*)d_in[8];  pa.a_Whh = (const float*)d_in[9];  pa.a_b = (const float*)d_in[10];
  pa.v_Wih = (const float*)d_in[11]; pa.v_Whh = (const float*)d_in[12]; pa.v_b = (const float*)d_in[13];
  pa.aW1 = (const float*)d_in[14];  pa.aW2 = (const float*)d_in[16];
  pa.bW1 = (const float*)d_in[18];  pa.bW2 = (const float*)d_in[20];
  pa.g1W1 = (const float*)d_in[22]; pa.g2W1 = (const float*)d_in[26];
  pa.g1W2 = (const float*)d_in[24]; pa.g2W2 = (const float*)d_in[28];
  pa.oW1 = (const float*)d_in[30];
  pa.Wg_t = Wg_t; pa.Wg_a = Wg_a; pa.Wg_v = Wg_v; pa.W_a1 = W_a1; pa.W_a2 = W_a2;
  pa.W_b1 = W_b1; pa.W_b2 = W_b2; pa.W_g1 = W_g1; pa.W_g2 = W_g2; pa.W_o1 = W_o1;
  pa.bg = bg;
  pack_w<<<3684, 256, 0, stream>>>(pa);

  MainArgs ma;
  ma.x_p = (const float*)d_in[0];
  ma.c_t = (const float*)d_in[1]; ma.c_a = (const float*)d_in[2]; ma.c_v = (const float*)d_in[3];
  ma.mem0 = (const float*)d_in[4];
  ma.Wg_t = Wg_t; ma.Wg_a = Wg_a; ma.Wg_v = Wg_v; ma.W_a1 = W_a1; ma.W_a2 = W_a2;
  ma.W_b1 = W_b1; ma.W_b2 = W_b2; ma.W_g1 = W_g1; ma.W_g2 = W_g2; ma.W_o1 = W_o1;
  ma.bg = bg;
  ma.a1b1 = (const float*)d_in[15]; ma.a1b2 = (const float*)d_in[17];
  ma.a2b1 = (const float*)d_in[19]; ma.a2b2 = (const float*)d_in[21];
  ma.g1b1 = (const float*)d_in[23]; ma.g1b2 = (const float*)d_in[25];
  ma.g2b1 = (const float*)d_in[27]; ma.g2b2 = (const float*)d_in[29];
  ma.ob1 = (const float*)d_in[31]; ma.oW2 = (const float*)d_in[32]; ma.ob2 = (const float*)d_in[33];
  ma.out = (float*)d_out;
  fused_seq<<<256, 512, 0, stream>>>(ma);
}

// Round 4
// 1696.583 us; speedup vs baseline: 1.0714x; 1.0714x over previous
//
#include <hip/hip_runtime.h>
#include <math.h>

typedef _Float16 f16;
typedef f16 f16x8 __attribute__((ext_vector_type(8)));
typedef float f32x4 __attribute__((ext_vector_type(4)));

#define MFMA16(a, b, c) __builtin_amdgcn_mfma_f32_16x16x32_f16((a), (b), (c), 0, 0, 0)

// ---------------------------------------------------------------------------
// ws layout (bytes):
//  Wg_t  fp16 [512][448]  @ 0        (gates t: cols 0:300 Wih, 320:448 Whh, rows n=4u+g)
//  Wg_a  fp16 [256][160]  @ 458752   (cols 0:81 Wih, 96:160 Whh)
//  Wg_v  fp16 [256][448]  @ 540672   (cols 0:371 Wih, 384:448 Whh)
//  W_a1  fp16 [128][512]  @ 770048
//  W_a2  fp16 [512][128]  @ 901120
//  W_b1  fp16 [128][512]  @ 1032192
//  W_b2  fp16 [256][128]  @ 1163264
//  W_g1  fp16 [256][768]  @ 1228800  rows 0:128 g1_W1, 128:256 g2_W1
//  W_g2  fp16 [512][128]  @ 1622016  rows 0:256 g1_W2, 256:512 g2_W2
//  W_o1  fp16 [128][512]  @ 1753088
//  bg    f32  [1024]      @ 1884160  gate bias, interleaved n=4u+g
//  X16   fp16 [20*4096][800] @ 2097152  (optional, if ws fits: x_p in f16,
//        segments: t @0 w320 (300+pad), a @320 w96 (81+pad), v @416 w384 (371+pad))
// ---------------------------------------------------------------------------

struct PackArgs {
  const float *t_Wih, *t_Whh, *t_b, *a_Wih, *a_Whh, *a_b, *v_Wih, *v_Whh, *v_b;
  const float *aW1, *aW2, *bW1, *bW2, *g1W1, *g2W1, *g1W2, *g2W2, *oW1;
  f16 *Wg_t, *Wg_a, *Wg_v, *W_a1, *W_a2, *W_b1, *W_b2, *W_g1, *W_g2, *W_o1;
  float *bg;
};

__global__ __launch_bounds__(256) void pack_w(PackArgs p) {
  int idx = blockIdx.x * 256 + threadIdx.x;
  if (idx < 229376) {  // Wg_t [512][448]
    int n = idx / 448, k = idx % 448;
    int srow = (n & 3) * 128 + (n >> 2);
    float v = (k < 300) ? p.t_Wih[srow * 300 + k]
                        : ((k >= 320) ? p.t_Whh[srow * 128 + k - 320] : 0.f);
    p.Wg_t[idx] = (f16)v; return;
  }
  idx -= 229376;
  if (idx < 40960) {  // Wg_a [256][160]
    int n = idx / 160, k = idx % 160;
    int srow = (n & 3) * 64 + (n >> 2);
    float v = (k < 81) ? p.a_Wih[srow * 81 + k]
                       : ((k >= 96) ? p.a_Whh[srow * 64 + k - 96] : 0.f);
    p.Wg_a[idx] = (f16)v; return;
  }
  idx -= 40960;
  if (idx < 114688) {  // Wg_v [256][448]
    int n = idx / 448, k = idx % 448;
    int srow = (n & 3) * 64 + (n >> 2);
    float v = (k < 371) ? p.v_Wih[srow * 371 + k]
                        : ((k >= 384) ? p.v_Whh[srow * 64 + k - 384] : 0.f);
    p.Wg_v[idx] = (f16)v; return;
  }
  idx -= 114688;
  if (idx < 65536) { p.W_a1[idx] = (f16)p.aW1[idx]; return; }
  idx -= 65536;
  if (idx < 65536) { p.W_a2[idx] = (f16)p.aW2[idx]; return; }
  idx -= 65536;
  if (idx < 65536) { p.W_b1[idx] = (f16)p.bW1[idx]; return; }
  idx -= 65536;
  if (idx < 32768) { p.W_b2[idx] = (f16)p.bW2[idx]; return; }
  idx -= 32768;
  if (idx < 196608) {  // W_g1 [256][768]
    int n = idx / 768;
    p.W_g1[idx] = (f16)((n < 128) ? p.g1W1[idx] : p.g2W1[idx - 98304]);
    return;
  }
  idx -= 196608;
  if (idx < 65536) {  // W_g2 [512][128]
    int n = idx / 128;
    p.W_g2[idx] = (f16)((n < 256) ? p.g1W2[idx] : p.g2W2[idx - 32768]);
    return;
  }
  idx -= 65536;
  if (idx < 65536) { p.W_o1[idx] = (f16)p.oW1[idx]; return; }
  idx -= 65536;
  if (idx < 1024) {
    int n = idx;
    float v;
    if (n < 512)      v = p.t_b[(n & 3) * 128 + (n >> 2)];
    else if (n < 768) { int m = n - 512; v = p.a_b[(m & 3) * 64 + (m >> 2)]; }
    else              { int m = n - 768; v = p.v_b[(m & 3) * 64 + (m >> 2)]; }
    p.bg[n] = v;
  }
}

// x_p f32 [20*4096][752] -> X16 f16 [20*4096][800] with padded aligned segments
__global__ __launch_bounds__(256) void conv_x(const float* __restrict__ x,
                                              f16* __restrict__ X16) {
  int g = blockIdx.x * 256 + threadIdx.x;  // 20*4096*100 groups of 8 cols
  int c0 = (g % 100) * 8;
  int row = g / 100;
  const float* src = x + (size_t)row * 752;
  f16 out[8];
#pragma unroll
  for (int j = 0; j < 8; ++j) {
    int c = c0 + j;
    float v;
    if (c < 320)      v = (c < 300) ? src[c] : 0.f;
    else if (c < 416) { int s = c - 320; v = (s < 81) ? src[300 + s] : 0.f; }
    else              { int s = c - 416; v = (s < 371) ? src[381 + s] : 0.f; }
    out[j] = (f16)v;
  }
  *(f16x8*)(X16 + (size_t)row * 800 + c0) = *(f16x8*)out;
}

struct MainArgs {
  const float *x_p, *c_t, *c_a, *c_v, *mem0;
  const f16 *X16;
  const f16 *Wg_t, *Wg_a, *Wg_v, *W_a1, *W_a2, *W_b1, *W_b2, *W_g1, *W_g2, *W_o1;
  const float *bg, *a1b1, *a1b2, *a2b1, *a2b2, *g1b1, *g1b2, *g2b1, *g2b2, *ob1, *oW2, *ob2;
  float *out;
};

__device__ __forceinline__ float sigm(float x) {
  return __builtin_amdgcn_rcpf(1.f + __expf(-x));
}
__device__ __forceinline__ float ftanh(float x) {
  float t = __expf(-2.f * fabsf(x));
  float r = (1.f - t) * __builtin_amdgcn_rcpf(1.f + t);
  return copysignf(r, x);
}

// ---- gate x/h fragment load (B-operand: lane&15 = batch row) --------------
template <int XF16, int KSX, int KSH, int XB, int KXR>
__device__ __forceinline__ void gate_load(const float* xrowf, const f16* xrow16,
                                          int hb, f16x8* ax, f16x8* ah,
                                          const f16 (*h16)[264], int l15, int lg) {
  if (XF16) {
#pragma unroll
    for (int ks = 0; ks < KSX; ++ks)
      ax[ks] = *(const f16x8*)(xrow16 + XB + 8 * lg + 32 * ks);
  } else {
#pragma unroll
    for (int ks = 0; ks < KSX; ++ks) {
      int kk = 32 * ks + 8 * lg;
      float t0[8];
      if (kk + 8 <= KXR) {
        float4 p0 = *(const float4*)(xrowf + kk);
        float4 p1 = *(const float4*)(xrowf + kk + 4);
        t0[0] = p0.x; t0[1] = p0.y; t0[2] = p0.z; t0[3] = p0.w;
        t0[4] = p1.x; t0[5] = p1.y; t0[6] = p1.z; t0[7] = p1.w;
      } else {
#pragma unroll
        for (int j = 0; j < 8; ++j) t0[j] = (kk + j < KXR) ? xrowf[kk + j] : 0.f;
      }
      f16x8 vv;
#pragma unroll
      for (int j = 0; j < 8; ++j) vv[j] = (f16)t0[j];
      ax[ks] = vv;
    }
  }
#pragma unroll
  for (int ks = 0; ks < KSH; ++ks)
    ah[ks] = *(const f16x8*)(&h16[l15][hb + 8 * lg + 32 * ks]);
  // NOTE: x-fragment slot/k mapping only needs to match the weight fragment's.
}

// ---- gate GEMM, SWAPPED operands: D rows = weight-n (=4u+gate), cols = batch
// Lane (l15,lg) q-th acc element = gate q of unit (nc0/4 + 4i + lg), row l15.
template <int KSX, int KSH, int KP>
__device__ __forceinline__ void gate_mm(const f16* Wc, const float* bg,
                                        int nc0, int n0, int cub,
                                        const f16x8* ax, const f16x8* ah,
                                        int l15, int lg,
                                        f16 (*h16)[264], float (*cS)[260],
                                        f16 (*bufA)[808]) {
#pragma unroll
  for (int i = 0; i < 8; ++i) {
    const f16* wrow = Wc + (size_t)(nc0 + 16 * i + l15) * KP + 8 * lg;
    f32x4 acc = {0.f, 0.f, 0.f, 0.f};
#pragma unroll
    for (int k = 0; k < KSX; ++k)
      acc = MFMA16(*(const f16x8*)(wrow + 32 * k), ax[k], acc);
#pragma unroll
    for (int k = 0; k < KSH; ++k)
      acc = MFMA16(*(const f16x8*)(wrow + 32 * (KSX + k)), ah[k], acc);
    const float4 bb = *(const float4*)&bg[n0 + 16 * i + 4 * lg];
    float gi = sigm(acc[0] + bb.x);
    float gf = sigm(acc[1] + bb.y);
    float gg = ftanh(acc[2] + bb.z);
    float go = sigm(acc[3] + bb.w);
    int cu = cub + ((nc0 + 16 * i) >> 2) + lg;
    float cold = cS[l15][cu];
    float cnew = gf * cold + gi * gg;
    cS[l15][cu] = cnew;
    h16[l15][cu] = (f16)(go * ftanh(cnew));
    bufA[l15][cu] = (f16)cold;        // c_star = [pre_c | cur_c]
    bufA[l15][256 + cu] = (f16)cnew;
  }
}

// ---- one 16-col output tile, K = KS*32, A from LDS (A: lane&15 = batch row)
template <int KS, int LDA>
__device__ __forceinline__ f32x4 fc_tile(const f16 (*Asrc)[LDA], int acol,
                                         const f16* Wrow, int l15, int lg) {
  f32x4 acc = {0.f, 0.f, 0.f, 0.f};
#pragma unroll
  for (int k = 0; k < KS; ++k) {
    f16x8 a = *(const f16x8*)(&Asrc[l15][acol + 8 * lg + 32 * k]);
    acc = MFMA16(a, *(const f16x8*)(Wrow + 32 * k), acc);
  }
  return acc;
}

// ---- g-hidden: K=768 from bufA, TILES 16-col tiles starting at tile st ----
template <int TILES>
__device__ __forceinline__ void ghidden_fn(const f16 (*bufA)[808], f16 (*ghid)[264],
                                           const f16* Wg1, const float* g1b1,
                                           const float* g2b1, int st, int l15, int lg) {
  f16x8 a[24];
#pragma unroll
  for (int k = 0; k < 24; ++k) a[k] = *(const f16x8*)(&bufA[l15][8 * lg + 32 * k]);
#pragma unroll
  for (int i = 0; i < TILES; ++i) {
    int nn = 16 * (st + i) + l15;
    const f16* wr = Wg1 + (size_t)nn * 768 + 8 * lg;
    f32x4 acc = {0.f, 0.f, 0.f, 0.f};
#pragma unroll
    for (int k = 0; k < 24; ++k) acc = MFMA16(a[k], *(const f16x8*)(wr + 32 * k), acc);
    float b = (nn < 128) ? g1b1[nn] : g2b1[nn - 128];
#pragma unroll
    for (int q = 0; q < 4; ++q) ghid[lg * 4 + q][nn] = (f16)fmaxf(acc[q] + b, 0.f);
  }
}

template <int XF16>
__global__ __launch_bounds__(512, 2) void fused_seq(MainArgs A) {
  __shared__ f16  h16[16][264];     // current h (fp16)
  __shared__ float cS[16][260];     // cell state f32
  __shared__ float mS[16][260];     // memory f32
  __shared__ f16  bufA[16][808];    // cstar/attended (0:512) | m fp16 (512:768)
  __shared__ f16  hid16[16][264];   // attn MLP hidden
  __shared__ f16  ghid16[16][264];  // g1|g2 hidden
  __shared__ float zf[16][516];     // attn1 logits

  const int tid = threadIdx.x;
  const int wid = tid >> 6, lane = tid & 63, l15 = lane & 15, lg = lane >> 4;
  const int r0 = blockIdx.x * 16;

  for (int idx = tid; idx < 4096; idx += 512) {
    int r = idx >> 8, c = idx & 255, R = r0 + r;
    h16[r][c] = (f16)0.f;
    float cv = (c < 128) ? A.c_t[R * 128 + c]
                         : (c < 192 ? A.c_a[R * 64 + c - 128] : A.c_v[R * 64 + c - 192]);
    cS[r][c] = cv;
    mS[r][c] = A.mem0[R * 256 + c];
  }
  __syncthreads();

#pragma unroll 1
  for (int t = 0; t < 20; ++t) {
    // ================= STAGE G: LSTM gates (swapped-operand MFMA) ==========
    const float* xrowf = A.x_p + ((size_t)t * 4096 + r0 + l15) * 752;
    const f16* xrow16 = A.X16 + ((size_t)t * 4096 + r0 + l15) * 800;
    f16x8 ax[12], ah[4];
    if (wid < 4)
      gate_load<XF16, 10, 4, 0, 300>(xrowf, xrow16, 0, ax, ah, h16, l15, lg);
    else if (wid < 6)
      gate_load<XF16, 3, 2, 320, 81>(xrowf + 300, xrow16, 128, ax, ah, h16, l15, lg);
    else
      gate_load<XF16, 12, 2, 416, 371>(xrowf + 381, xrow16, 192, ax, ah, h16, l15, lg);
    __syncthreads();  // h frags in regs before h16/bufA/cS writes
    if (wid < 4)
      gate_mm<10, 4, 448>(A.Wg_t, A.bg, 128 * wid, 128 * wid, 0, ax, ah, l15, lg, h16, cS, bufA);
    else if (wid < 6)
      gate_mm<3, 2, 160>(A.Wg_a, A.bg, 128 * (wid - 4), 512 + 128 * (wid - 4), 128, ax, ah, l15, lg, h16, cS, bufA);
    else
      gate_mm<12, 2, 448>(A.Wg_v, A.bg, 128 * (wid - 6), 768 + 128 * (wid - 6), 192, ax, ah, l15, lg, h16, cS, bufA);
    __syncthreads();

    // ================= attn1 L1: hid = relu(cstar @ W^T + b) ===============
    {
      int n = 16 * wid;
      f32x4 acc = fc_tile<16, 808>(bufA, 0, A.W_a1 + (size_t)(n + l15) * 512 + 8 * lg, l15, lg);
      float b = A.a1b1[n + l15];
#pragma unroll
      for (int q = 0; q < 4; ++q) hid16[lg * 4 + q][n + l15] = (f16)fmaxf(acc[q] + b, 0.f);
    }
    __syncthreads();

    // ================= attn1 L2: logits, 4 tiles/wave ======================
    {
      f16x8 a[4];
#pragma unroll
      for (int k = 0; k < 4; ++k) a[k] = *(const f16x8*)(&hid16[l15][8 * lg + 32 * k]);
#pragma unroll
      for (int i = 0; i < 4; ++i) {
        int n = 64 * wid + 16 * i + l15;
        const f16* wr = A.W_a2 + (size_t)n * 128 + 8 * lg;
        f32x4 acc = {0.f, 0.f, 0.f, 0.f};
#pragma unroll
        for (int k = 0; k < 4; ++k) acc = MFMA16(a[k], *(const f16x8*)(wr + 32 * k), acc);
        float b = A.a1b2[n];
#pragma unroll
        for (int q = 0; q < 4; ++q) zf[lg * 4 + q][n] = acc[q] + b;
      }
    }
    __syncthreads();

    // ================= softmax * cstar (in place), m -> bufA[512:768] ======
    {
      int row = tid >> 5, c0 = tid & 31;
      float v[16]; float mx = -1e30f;
#pragma unroll
      for (int j = 0; j < 16; ++j) { v[j] = zf[row][c0 + 32 * j]; mx = fmaxf(mx, v[j]); }
#pragma unroll
      for (int m = 1; m < 32; m <<= 1) mx = fmaxf(mx, __shfl_xor(mx, m));
      float s = 0.f;
#pragma unroll
      for (int j = 0; j < 16; ++j) { v[j] = __expf(v[j] - mx); s += v[j]; }
#pragma unroll
      for (int m = 1; m < 32; m <<= 1) s += __shfl_xor(s, m);
      float inv = __builtin_amdgcn_rcpf(s);
#pragma unroll
      for (int j = 0; j < 16; ++j) {
        int c = c0 + 32 * j;
        bufA[row][c] = (f16)(v[j] * inv * (float)bufA[row][c]);
      }
      for (int idx = tid; idx < 4096; idx += 512) {
        int r = idx >> 8, c = idx & 255;
        bufA[r][512 + c] = (f16)mS[r][c];
      }
    }
    __syncthreads();

    // ====== attn2 L1 (waves 6,7: 4 tiles) || g-hidden (waves 0-5) ==========
    if (wid >= 6) {
#pragma unroll
      for (int i = 0; i < 4; ++i) {
        int n = 64 * (wid - 6) + 16 * i;
        f32x4 acc = fc_tile<16, 808>(bufA, 0, A.W_b1 + (size_t)(n + l15) * 512 + 8 * lg, l15, lg);
        float b = A.a2b1[n + l15];
#pragma unroll
        for (int q = 0; q < 4; ++q) hid16[lg * 4 + q][n + l15] = (f16)fmaxf(acc[q] + b, 0.f);
      }
    } else if (wid < 4) {
      ghidden_fn<3>(bufA, ghid16, A.W_g1, A.g1b1, A.g2b1, 3 * wid, l15, lg);
    } else {
      ghidden_fn<2>(bufA, ghid16, A.W_g1, A.g1b1, A.g2b1, 12 + 2 * (wid - 4), l15, lg);
    }
    __syncthreads();

    // ====== fused: attn2 L2 + g1/g2 second layers + m-update (chat in regs)
    {
      f16x8 ha[4], ga1[4], ga2[4];
#pragma unroll
      for (int k = 0; k < 4; ++k) {
        ha[k] = *(const f16x8*)(&hid16[l15][8 * lg + 32 * k]);
        ga1[k] = *(const f16x8*)(&ghid16[l15][8 * lg + 32 * k]);
        ga2[k] = *(const f16x8*)(&ghid16[l15][128 + 8 * lg + 32 * k]);
      }
#pragma unroll
      for (int i = 0; i < 2; ++i) {
        int n = 32 * wid + 16 * i + l15;
        const f16* wb = A.W_b2 + (size_t)n * 128 + 8 * lg;
        const f16* w1 = A.W_g2 + (size_t)n * 128 + 8 * lg;
        const f16* w2 = A.W_g2 + (size_t)(256 + n) * 128 + 8 * lg;
        f32x4 acB = {0.f, 0.f, 0.f, 0.f};
        f32x4 ac1 = {0.f, 0.f, 0.f, 0.f};
        f32x4 ac2 = {0.f, 0.f, 0.f, 0.f};
#pragma unroll
        for (int k = 0; k < 4; ++k) {
          acB = MFMA16(ha[k], *(const f16x8*)(wb + 32 * k), acB);
          ac1 = MFMA16(ga1[k], *(const f16x8*)(w1 + 32 * k), ac1);
          ac2 = MFMA16(ga2[k], *(const f16x8*)(w2 + 32 * k), ac2);
        }
        float bB = A.a2b2[n], b1 = A.g1b2[n], b2 = A.g2b2[n];
#pragma unroll
        for (int q = 0; q < 4; ++q) {
          int row = lg * 4 + q;
          float ch = ftanh(acB[q] + bB);
          float g1 = sigm(ac1[q] + b1);
          float g2 = sigm(ac2[q] + b2);
          mS[row][n] = g1 * mS[row][n] + g2 * ch;
        }
      }
    }
    __syncthreads();
  }

  // ================= output head ==========================================
  for (int idx = tid; idx < 4096; idx += 512) {
    int r = idx >> 8, c = idx & 255;
    bufA[r][c] = h16[r][c];
    bufA[r][256 + c] = (f16)mS[r][c];
  }
  __syncthreads();
  {
    int n = 16 * wid;
    f32x4 acc = fc_tile<16, 808>(bufA, 0, A.W_o1 + (size_t)(n + l15) * 512 + 8 * lg, l15, lg);
    float b = A.ob1[n + l15];
#pragma unroll
    for (int q = 0; q < 4; ++q) hid16[lg * 4 + q][n + l15] = (f16)fmaxf(acc[q] + b, 0.f);
  }
  __syncthreads();
  {
    int row = tid >> 5, c0 = tid & 31;
    float s = 0.f;
#pragma unroll
    for (int j = 0; j < 4; ++j) { int k = c0 + 32 * j; s += (float)hid16[row][k] * A.oW2[k]; }
#pragma unroll
    for (int m = 1; m < 32; m <<= 1) s += __shfl_xor(s, m);
    if (c0 == 0) A.out[r0 + row] = s + A.ob2[0];
  }
}

extern "C" void kernel_launch(void* const* d_in, const int* in_sizes, int n_in,
                              void* d_out, int out_size, void* d_ws, size_t ws_size,
                              hipStream_t stream) {
  (void)in_sizes; (void)n_in; (void)out_size;
  char* w = (char*)d_ws;
  f16* Wg_t = (f16*)(w + 0);
  f16* Wg_a = (f16*)(w + 458752);
  f16* Wg_v = (f16*)(w + 540672);
  f16* W_a1 = (f16*)(w + 770048);
  f16* W_a2 = (f16*)(w + 901120);
  f16* W_b1 = (f16*)(w + 1032192);
  f16* W_b2 = (f16*)(w + 1163264);
  f16* W_g1 = (f16*)(w + 1228800);
  f16* W_g2 = (f16*)(w + 1622016);
  f16* W_o1 = (f16*)(w + 1753088);
  float* bg = (float*)(w + 1884160);
  f16* X16 = (f16*)(w + 2097152);
  const size_t X16_BYTES = (size_t)20 * 4096 * 800 * sizeof(f16);  // 131 MB
  const int use_xf16 = (ws_size >= 2097152 + X16_BYTES) ? 1 : 0;

  PackArgs pa;
  pa.t_Wih = (const float*)d_in[5];  pa.t_Whh = (const float*)d_in[6];  pa.t_b = (const float*)d_in[7];
  pa.a_Wih = (const float*)d_in[8];  pa.a_Whh = (const float*)d_in[9];  pa.a_b = (const float*)d_in[10];
  pa.v_Wih = (const float*)d_in[11]; pa.v_Whh = (const float*)d_in[12]; pa.v_b = (const float*)d_in[13];
  pa.aW1 = (const float*)d_in[14];  pa.aW2 = (const float*)d_in[16];
  pa.bW1 = (const float*)d_in[18];  pa.bW2 = (const float*)d_in[20];
  pa.g1W1 = (const float*)d_in[22]; pa.g2W1 = (const float*)d_in[26];
  pa.g1W2 = (const float*)d_in[24]; pa.g2W2 = (const float*)d_in[28];
  pa.oW1 = (const float*)d_in[30];
  pa.Wg_t = Wg_t; pa.Wg_a = Wg_a; pa.Wg_v = Wg_v; pa.W_a1 = W_a1; pa.W_a2 = W_a2;
  pa.W_b1 = W_b1; pa.W_b2 = W_b2; pa.W_g1 = W_g1; pa.W_g2 = W_g2; pa.W_o1 = W_o1;
  pa.bg = bg;
  pack_w<<<3684, 256, 0, stream>>>(pa);
  if (use_xf16) conv_x<<<32000, 256, 0, stream>>>((const float*)d_in[0], X16);

  MainArgs ma;
  ma.x_p = (const float*)d_in[0];
  ma.c_t = (const float*)d_in[1]; ma.c_a = (const float*)d_in[2]; ma.c_v = (const float*)d_in[3];
  ma.mem0 = (const float*)d_in[4];
  ma.X16 = X16;
  ma.Wg_t = Wg_t; ma.Wg_a = Wg_a; ma.Wg_v = Wg_v; ma.W_a1 = W_a1; ma.W_a2 = W_a2;
  ma.W_b1 = W_b1; ma.W_b2 = W_b2; ma.W_g1 = W_g1; ma.W_g2 = W_g2; ma.W_o1 = W_o1;
  ma.bg = bg;
  ma.a1b1 = (const float*)d_in[15]; ma.a1b2 = (const float*)d_in[17];
  ma.a2b1 = (const float*)d_in[19]; ma.a2b2 = (const float*)d_in[21];
  ma.g1b1 = (const float*)d_in[23]; ma.g1b2 = (const float*)d_in[25];
  ma.g2b1 = (const float*)d_in[27]; ma.g2b2 = (const float*)d_in[29];
  ma.ob1 = (const float*)d_in[31]; ma.oW2 = (const float*)d_in[32]; ma.ob2 = (const float*)d_in[33];
  ma.out = (float*)d_out;
  if (use_xf16) fused_seq<1><<<256, 512, 0, stream>>>(ma);
  else          fused_seq<0><<<256, 512, 0, stream>>>(ma);
}